// Round 1
// baseline (95.676 us; speedup 1.0000x reference)
//
#include <hip/hip_runtime.h>

// KANSpline1D: out = id_gain[c]*x + spline(clip(a[c]*x+b[c],-1.5,1.5)) + bias[c]
// B=16, C=128, H=64, W=64, K=16 cubic B-spline basis, open-uniform knots on [-1,1].
// Memory-bound: 67 MB traffic -> ~11 us roofline.

#define N_TOTAL (16 * 128 * 64 * 64)

__global__ __launch_bounds__(256) void kan_spline_kernel(
    const float* __restrict__ x,
    const float* __restrict__ a,
    const float* __restrict__ b,
    const float* __restrict__ alpha,   // [128][16]
    const float* __restrict__ gain,
    const float* __restrict__ bias,
    float* __restrict__ out,
    int n4)
{
    int i = blockIdx.x * blockDim.x + threadIdx.x;
    if (i >= n4) return;

    // element base = 4*i; channel = (4*i / 4096) % 128 = (i >> 10) & 127
    // wave spans 64 consecutive i -> channel is wave-uniform (1024 % 64 == 0)
    const int c = (i >> 10) & 127;
    const float ac  = a[c];
    const float bc  = b[c];
    const float gc  = gain[c];
    const float bic = bias[c];
    const float* __restrict__ ar = alpha + (c << 4);

    const float h    = 2.0f / 13.0f;
    const float invh = 6.5f;           // 1/h

    float4 xv = reinterpret_cast<const float4*>(x)[i];
    float4 ov;

    // knot(m) = clamp(-1 + (m-3)*h, -1, 1), m in [0,19]
    auto knot = [&](int m) -> float {
        return fminf(fmaxf(fmaf((float)(m - 3), h, -1.0f), -1.0f), 1.0f);
    };
    // 1/(knot[m+3]-knot[m]); m in [1,15]
    auto invD3 = [&](int m) -> float {
        return (m == 1 || m == 15) ? invh
             : ((m == 2 || m == 14) ? 0.5f * invh : invh * (1.0f / 3.0f));
    };

#pragma unroll
    for (int e = 0; e < 4; ++e) {
        const float xs = (&xv.x)[e];
        float t = fminf(fmaxf(fmaf(xs, ac, bc), -1.5f), 1.5f);

        // span: relative s in [0,12], absolute j = s+3 so t in [knot(j), knot(j+1))
        int s = (int)floorf((t + 1.0f) * invh);
        s = min(max(s, 0), 12);
        const int j = s + 3;

        const float left1  = t - knot(j);
        const float right1 = knot(j + 1) - t;
        const float left2  = t - knot(j - 1);
        const float right2 = knot(j + 2) - t;
        const float left3  = t - knot(j - 2);
        const float right3 = knot(j + 3) - t;

        // 1/(knot[m+2]-knot[m]): m=j-1 in [2,14] (h only at m=2); m=j in [3,15] (h only at m=15)
        const float invD2_jm1 = (j == 3)  ? invh : 0.5f * invh;
        const float invD2_j   = (j == 15) ? invh : 0.5f * invh;
        const float invD3_jm2 = invD3(j - 2);
        const float invD3_jm1 = invD3(j - 1);
        const float invD3_j   = invD3(j);

        // de Boor basis evaluation (degree 3), all denominators pre-inverted
        float N0, N1, N2, N3, temp, saved;
        // r = 1  (den = D1[j] = h always for j in [3,15])
        temp = invh;                 // N[0]=1 times 1/h
        N0 = right1 * temp;
        N1 = left1 * temp;
        // r = 2
        temp  = N0 * invD2_jm1;
        N0    = right1 * temp;
        saved = left2 * temp;
        temp  = N1 * invD2_j;
        N1    = saved + right2 * temp;
        N2    = left1 * temp;
        // r = 3
        temp  = N0 * invD3_jm2;
        N0    = right1 * temp;
        saved = left3 * temp;
        temp  = N1 * invD3_jm1;
        N1    = saved + right2 * temp;
        saved = left2 * temp;
        temp  = N2 * invD3_j;
        N2    = saved + right3 * temp;
        N3    = left1 * temp;

        float spline = N0 * ar[s] + N1 * ar[s + 1] + N2 * ar[s + 2] + N3 * ar[s + 3];

        // Outside [-1,1): all basis vanish. At t==1 exactly the reference's
        // one-hot lands in the degenerate [1,1) interval and is annihilated by
        // the zero-denominator masking -> reference is also 0 there.
        const bool inside = (t >= -1.0f) && (t < 1.0f);
        spline = inside ? spline : 0.0f;

        (&ov.x)[e] = fmaf(gc, xs, spline + bic);
    }

    reinterpret_cast<float4*>(out)[i] = ov;
}

extern "C" void kernel_launch(void* const* d_in, const int* in_sizes, int n_in,
                              void* d_out, int out_size, void* d_ws, size_t ws_size,
                              hipStream_t stream) {
    const float* x     = (const float*)d_in[0];
    const float* a     = (const float*)d_in[1];
    const float* b     = (const float*)d_in[2];
    const float* alpha = (const float*)d_in[3];
    const float* gain  = (const float*)d_in[4];
    const float* bias  = (const float*)d_in[5];
    float* out = (float*)d_out;

    const int n4 = out_size / 4;           // 2,097,152 float4 groups
    const int block = 256;
    const int grid = (n4 + block - 1) / block;   // 8192 blocks
    kan_spline_kernel<<<grid, block, 0, stream>>>(x, a, b, alpha, gain, bias, out, n4);
}

// Round 2
// 95.365 us; speedup vs baseline: 1.0033x; 1.0033x over previous
//
#include <hip/hip_runtime.h>

// KANSpline1D: out = id_gain[c]*x + spline(clip(a[c]*x+b[c],-1.5,1.5)) + bias[c]
// B=16, C=128, H=64, W=64, K=16 cubic B-spline, open-uniform knots on [-1,1],
// interior spacing h=2/13, 13 real spans (j=3..15).
//
// Two-phase: (A) tiny kernel builds per-(channel,span) cubic Horner coeffs in
// local coord u in [0,1]  ->  d_ws[c*13+s] as float4 {c0,c1,c2,c3};
// (B) main kernel: 1 float4-gather + 3-FMA Horner per element. Memory-bound
// target: 67 MB @ ~6.3 TB/s ~= 11 us.

__device__ __forceinline__ float knot_val(int m) {
    const float h = 2.0f / 13.0f;
    return fminf(fmaxf(fmaf((float)(m - 3), h, -1.0f), -1.0f), 1.0f);
}

// Evaluate the 4 basis polys of span j (j in [3,15]) at t, as polynomials
// (no support masking -- valid extension at span edges).
__device__ __forceinline__ void basis_span(float t, int j,
                                           float& N0, float& N1, float& N2, float& N3) {
    const float invh = 6.5f;
    auto invD3 = [&](int m) -> float {
        return (m == 1 || m == 15) ? invh
             : ((m == 2 || m == 14) ? 0.5f * invh : invh * (1.0f / 3.0f));
    };
    const float left1  = t - knot_val(j);
    const float right1 = knot_val(j + 1) - t;
    const float left2  = t - knot_val(j - 1);
    const float right2 = knot_val(j + 2) - t;
    const float left3  = t - knot_val(j - 2);
    const float right3 = knot_val(j + 3) - t;
    const float invD2_jm1 = (j == 3)  ? invh : 0.5f * invh;
    const float invD2_j   = (j == 15) ? invh : 0.5f * invh;

    float temp, saved;
    temp = invh;
    N0 = right1 * temp;
    N1 = left1 * temp;
    temp  = N0 * invD2_jm1;
    N0    = right1 * temp;
    saved = left2 * temp;
    temp  = N1 * invD2_j;
    N1    = saved + right2 * temp;
    N2    = left1 * temp;
    temp  = N0 * invD3(j - 2);
    N0    = right1 * temp;
    saved = left3 * temp;
    temp  = N1 * invD3(j - 1);
    N1    = saved + right2 * temp;
    saved = left2 * temp;
    temp  = N2 * invD3(j);
    N2    = saved + right3 * temp;
    N3    = left1 * temp;
}

// Phase A: one thread per (channel, span). 128*13 = 1664 threads.
__global__ __launch_bounds__(256) void kan_coeff_kernel(
    const float* __restrict__ alpha,   // [128][16]
    float4* __restrict__ coef)         // [128][13]
{
    int tid = blockIdx.x * blockDim.x + threadIdx.x;
    if (tid >= 128 * 13) return;
    const int c = tid / 13;
    const int s = tid - c * 13;
    const int j = s + 3;
    const float h = 2.0f / 13.0f;

    const float a0 = alpha[(c << 4) + s];
    const float a1 = alpha[(c << 4) + s + 1];
    const float a2 = alpha[(c << 4) + s + 2];
    const float a3 = alpha[(c << 4) + s + 3];

    float y[4];
#pragma unroll
    for (int k = 0; k < 4; ++k) {
        const float u = (float)k * (1.0f / 3.0f);
        const float t = fmaf((float)s + u, h, -1.0f);
        float N0, N1, N2, N3;
        basis_span(t, j, N0, N1, N2, N3);
        y[k] = N0 * a0 + N1 * a1 + N2 * a2 + N3 * a3;
    }
    // Newton forward differences on z = 3u in {0,1,2,3}; exact for cubics.
    const float d1 = y[1] - y[0];
    const float d2 = y[2] - 2.0f * y[1] + y[0];
    const float d3 = y[3] - 3.0f * y[2] + 3.0f * y[1] - y[0];
    float4 cf;
    cf.x = y[0];
    cf.y = 3.0f * d1 - 1.5f * d2 + d3;
    cf.z = 4.5f * d2 - 4.5f * d3;
    cf.w = 4.5f * d3;
    coef[tid] = cf;
}

// Phase B: 1 float4 of x per thread.
__global__ __launch_bounds__(256) void kan_spline_kernel(
    const float* __restrict__ x,
    const float* __restrict__ a,
    const float* __restrict__ b,
    const float* __restrict__ gain,
    const float* __restrict__ bias,
    const float4* __restrict__ coef,   // [128][13]
    float* __restrict__ out,
    int n4)
{
    int i = blockIdx.x * blockDim.x + threadIdx.x;
    if (i >= n4) return;

    // 4*i element base; channel = (i>>10)&127 -- block-uniform (256 | 1024)
    const int c = (i >> 10) & 127;
    const float ac  = a[c];
    const float bc  = b[c];
    const float gc  = gain[c];
    const float bic = bias[c];
    const float4* __restrict__ Ct = coef + c * 13;

    float4 xv = reinterpret_cast<const float4*>(x)[i];
    float4 ov;

#pragma unroll
    for (int e = 0; e < 4; ++e) {
        const float xs = (&xv.x)[e];
        const float t = fminf(fmaxf(fmaf(xs, ac, bc), -1.5f), 1.5f);
        const float f = fmaf(t, 6.5f, 6.5f);        // (t+1)/h
        int s = (int)f;                              // trunc; negatives masked anyway
        s = min(max(s, 0), 12);
        const float u = f - (float)s;                // u in [0,1) on valid spans
        const float4 cf = Ct[s];
        float p = fmaf(fmaf(fmaf(cf.w, u, cf.z), u, cf.y), u, cf.x);
        // Outside [-1,1) every basis vanishes (incl. reference's t==1 edge case).
        p = (t >= -1.0f && t < 1.0f) ? p : 0.0f;
        (&ov.x)[e] = fmaf(gc, xs, p + bic);
    }

    reinterpret_cast<float4*>(out)[i] = ov;
}

extern "C" void kernel_launch(void* const* d_in, const int* in_sizes, int n_in,
                              void* d_out, int out_size, void* d_ws, size_t ws_size,
                              hipStream_t stream) {
    const float* x     = (const float*)d_in[0];
    const float* a     = (const float*)d_in[1];
    const float* b     = (const float*)d_in[2];
    const float* alpha = (const float*)d_in[3];
    const float* gain  = (const float*)d_in[4];
    const float* bias  = (const float*)d_in[5];
    float* out = (float*)d_out;
    float4* coef = (float4*)d_ws;                  // 128*13*16 B = 26.6 KB

    kan_coeff_kernel<<<(128 * 13 + 255) / 256, 256, 0, stream>>>(alpha, coef);

    const int n4 = out_size / 4;                   // 2,097,152
    const int block = 256;
    const int grid = (n4 + block - 1) / block;     // 8192 blocks
    kan_spline_kernel<<<grid, block, 0, stream>>>(x, a, b, gain, bias, coef, out, n4);
}